// Round 2
// baseline (903.260 us; speedup 1.0000x reference)
//
#include <hip/hip_runtime.h>
#include <hip/hip_bf16.h>

#define CC 128
#define NN 32768
#define QSCALE 0.17677669529663687f  /* 1/sqrt(32) */

/* ws layout (float offsets) */
#define WQT_OFF   0          /* [8][128][32]  q weights transposed           */
#define WKVT_OFF  32768      /* [8][128][64]  k(0..31)|v(32..63) transposed  */
#define PART_OFF  98304      /* [2048 blocks][2112] per-block kv partials    */
#define PACC_OFF  4423680    /* [4][8][32][32] reduced sum exp(k)*v          */
#define SACC_OFF  4456448    /* [4][8][32]     reduced sum exp(k)            */
#define MT_OFF    4457472    /* [4][256][128]  M transposed                  */

/* ---- prep: transpose fp32 weights so inner loops do contiguous uniform loads ---- */
__global__ void prep_kernel(const float* __restrict__ wqkv, float* __restrict__ ws) {
    int idx = blockIdx.x * 256 + threadIdx.x;
    if (idx < 32768) {                       /* wqT[h][c][r] */
        int h = idx >> 12;
        int c = (idx >> 5) & 127;
        int r = idx & 31;
        ws[WQT_OFF + idx] = wqkv[(h * 32 + r) * 128 + c];
    } else if (idx < 98304) {                /* wkvT[h][c][j] */
        int i2 = idx - 32768;
        int h = i2 >> 13;
        int c = (i2 >> 6) & 127;
        int j = i2 & 63;
        int row = (j < 32) ? (256 + h * 32 + j) : (512 + h * 32 + (j - 32));
        ws[WKVT_OFF + i2] = wqkv[row * 128 + c];
    }
}

/* ---- Kernel A: k,v logits (2 heads/block) + per-block context partials ---- */
__global__ __launch_bounds__(256) void kv_context_kernel(
        const float* __restrict__ x, const float* __restrict__ ws,
        float* __restrict__ part) {
    __shared__ float e_lds[256 * 33];   /* [col][d] pitch 33 : conflict-free */
    __shared__ float v_lds[32 * 257];   /* [e][col] pitch 257 */
    int blk = blockIdx.x;               /* 2048 = b(4) x tg(128) x hp(4), hp fastest */
    int hp = blk & 3;
    int tg = (blk >> 2) & 127;
    int b  = blk >> 9;
    int tid = threadIdx.x;
    const float* w0 = ws + WKVT_OFF + (hp * 2 + 0) * (128 * 64);
    const float* w1 = ws + WKVT_OFF + (hp * 2 + 1) * (128 * 64);
    const float* xcol = x + (size_t)b * CC * NN + tg * 256 + tid;
    float kc0[32], vc0[32], kc1[32], vc1[32];
    #pragma unroll
    for (int j = 0; j < 32; ++j) { kc0[j] = 0.f; vc0[j] = 0.f; kc1[j] = 0.f; vc1[j] = 0.f; }
    #pragma unroll 2
    for (int c = 0; c < 128; ++c) {
        float xv = xcol[(size_t)c * NN];
        #pragma unroll
        for (int j = 0; j < 32; ++j) kc0[j] += w0[c * 64 + j] * xv;
        #pragma unroll
        for (int j = 0; j < 32; ++j) vc0[j] += w0[c * 64 + 32 + j] * xv;
        #pragma unroll
        for (int j = 0; j < 32; ++j) kc1[j] += w1[c * 64 + j] * xv;
        #pragma unroll
        for (int j = 0; j < 32; ++j) vc1[j] += w1[c * 64 + 32 + j] * xv;
    }
    int r8 = tid >> 3;
    int e0 = (tid & 7) << 2;
    float* pbase = part + (size_t)blk * 2112;
    #pragma unroll 1
    for (int hi = 0; hi < 2; ++hi) {
        __syncthreads();
        #pragma unroll
        for (int j = 0; j < 32; ++j)
            e_lds[tid * 33 + j] = __expf(hi == 0 ? kc0[j] : kc1[j]);
        #pragma unroll
        for (int j = 0; j < 32; ++j)
            v_lds[j * 257 + tid] = (hi == 0 ? vc0[j] : vc1[j]);
        __syncthreads();
        float P0 = 0.f, P1 = 0.f, P2 = 0.f, P3 = 0.f;
        #pragma unroll 2
        for (int col = 0; col < 256; ++col) {
            float ev = e_lds[col * 33 + r8];
            P0 += ev * v_lds[(e0 + 0) * 257 + col];
            P1 += ev * v_lds[(e0 + 1) * 257 + col];
            P2 += ev * v_lds[(e0 + 2) * 257 + col];
            P3 += ev * v_lds[(e0 + 3) * 257 + col];
        }
        int pb = hi * 1024 + r8 * 32 + e0;
        pbase[pb + 0] = P0; pbase[pb + 1] = P1; pbase[pb + 2] = P2; pbase[pb + 3] = P3;
        if (tid < 32) {
            float s = 0.f;
            #pragma unroll 4
            for (int col = 0; col < 256; ++col) s += e_lds[col * 33 + tid];
            pbase[2048 + hi * 32 + tid] = s;
        }
    }
}

/* ---- Kernel B1: reduce per-block partials -> Pacc, sacc ---- */
__global__ void reduce_kernel(const float* __restrict__ part,
                              float* __restrict__ Pacc, float* __restrict__ sacc) {
    int blk = blockIdx.x;               /* 32 = b(4) x h(8) */
    int h = blk & 7;
    int b = blk >> 3;
    int hp = h >> 1, hi = h & 1;
    int tid = threadIdx.x;              /* 256 */
    float a0 = 0.f, a1 = 0.f, a2 = 0.f, a3 = 0.f, s = 0.f;
    for (int tg = 0; tg < 128; ++tg) {
        const float* pb = part + (size_t)(((b * 128 + tg) * 4) + hp) * 2112 + hi * 1024;
        a0 += pb[tid];
        a1 += pb[tid + 256];
        a2 += pb[tid + 512];
        a3 += pb[tid + 768];
        if (tid < 32) s += pb[1024 + hi * 32 + tid - hi * 1024 + 1024];  /* see below */
    }
    /* fix s indexing cleanly: recompute (compiler folds) */
    if (tid < 32) {
        s = 0.f;
        for (int tg = 0; tg < 128; ++tg) {
            const float* pb = part + (size_t)(((b * 128 + tg) * 4) + hp) * 2112;
            s += pb[2048 + hi * 32 + tid];
        }
        sacc[(b * 8 + h) * 32 + tid] = s;
    }
    int obase = (b * 8 + h) * 1024;
    Pacc[obase + tid] = a0;
    Pacc[obase + tid + 256] = a1;
    Pacc[obase + tid + 512] = a2;
    Pacc[obase + tid + 768] = a3;
}

/* ---- Kernel B2: fold w_out into context -> MT[b][hd][cout] ---- */
__global__ void context_proj_kernel(const float* __restrict__ wout,
                                    const float* __restrict__ Pacc,
                                    const float* __restrict__ sacc,
                                    float* __restrict__ MT) {
    int blk = blockIdx.x;               /* 1024 = b(4) x hd(256) */
    int hd = blk & 255;
    int b  = blk >> 8;
    int h = hd >> 5, d = hd & 31;
    int cout = threadIdx.x;             /* 128 threads */
    float inv = 1.0f / sacc[(b * 8 + h) * 32 + d];
    const float* Prow = Pacc + (size_t)((b * 8 + h) * 32 + d) * 32;
    float a = 0.f;
    #pragma unroll
    for (int e = 0; e < 32; ++e)
        a += wout[cout * 256 + h * 32 + e] * Prow[e];
    MT[((size_t)b * 256 + hd) * 128 + cout] = a * inv;
}

/* ---- Kernel C: q logits -> per-head softmax -> out = M @ qsm + bias ---- */
__global__ __launch_bounds__(256) void q_out_kernel(
        const float* __restrict__ x, const float* __restrict__ ws,
        const float* __restrict__ MT, const float* __restrict__ bout,
        float* __restrict__ out) {
    __shared__ float qs_lds[32 * 256];  /* round-trip so d can be a rolled loop var */
    int blk = blockIdx.x;               /* 512 = b(4) x tile(128) */
    int b = blk >> 7;
    int tile = blk & 127;
    int tid = threadIdx.x;
    int col = tile * 256 + tid;
    const float* xcol = x + (size_t)b * CC * NN + col;
    float acc[128];
    #pragma unroll
    for (int i = 0; i < 128; ++i) acc[i] = bout[i];
    #pragma unroll 1
    for (int h = 0; h < 8; ++h) {
        const float* w = ws + WQT_OFF + h * (128 * 32);
        float q[32];
        #pragma unroll
        for (int r = 0; r < 32; ++r) q[r] = 0.f;
        #pragma unroll 2
        for (int c = 0; c < 128; ++c) {
            float xv = xcol[(size_t)c * NN];
            #pragma unroll
            for (int r = 0; r < 32; ++r) q[r] += w[c * 32 + r] * xv;
        }
        float m = q[0];
        #pragma unroll
        for (int r = 1; r < 32; ++r) m = fmaxf(m, q[r]);
        float sum = 0.f;
        #pragma unroll
        for (int r = 0; r < 32; ++r) { q[r] = __expf(q[r] - m); sum += q[r]; }
        float sc = QSCALE / sum;
        #pragma unroll
        for (int r = 0; r < 32; ++r) qs_lds[r * 256 + tid] = q[r] * sc;
        const float* Mb = MT + ((size_t)b * 256 + h * 32) * 128;
        #pragma unroll 1
        for (int d = 0; d < 32; ++d) {
            float qv = qs_lds[d * 256 + tid];
            #pragma unroll
            for (int i = 0; i < 128; ++i) acc[i] += Mb[d * 128 + i] * qv;
        }
    }
    size_t obase = (size_t)b * CC * NN + col;
    #pragma unroll
    for (int i = 0; i < 128; ++i)
        out[obase + (size_t)i * NN] = acc[i];
}

extern "C" void kernel_launch(void* const* d_in, const int* in_sizes, int n_in,
                              void* d_out, int out_size, void* d_ws, size_t ws_size,
                              hipStream_t stream) {
    (void)in_sizes; (void)n_in; (void)out_size; (void)ws_size;
    const float* x    = (const float*)d_in[0];
    const float* wqkv = (const float*)d_in[1];
    const float* wout = (const float*)d_in[2];
    const float* bout = (const float*)d_in[3];
    float* out = (float*)d_out;
    float* ws = (float*)d_ws;

    prep_kernel<<<384, 256, 0, stream>>>(wqkv, ws);
    kv_context_kernel<<<2048, 256, 0, stream>>>(x, ws, ws + PART_OFF);
    reduce_kernel<<<32, 256, 0, stream>>>(ws + PART_OFF, ws + PACC_OFF, ws + SACC_OFF);
    context_proj_kernel<<<1024, 128, 0, stream>>>(wout, ws + PACC_OFF, ws + SACC_OFF,
                                                  ws + MT_OFF);
    q_out_kernel<<<512, 256, 0, stream>>>(x, ws, ws + MT_OFF, bout, out);
}

// Round 3
// 440.722 us; speedup vs baseline: 2.0495x; 2.0495x over previous
//
#include <hip/hip_runtime.h>
#include <hip/hip_bf16.h>

#define CC 128
#define NN 32768
#define QSCALE 0.17677669529663687f  /* 1/sqrt(32) */

typedef unsigned short ushort_t;
typedef __attribute__((ext_vector_type(8))) short bf16x8;   /* 8 bf16 = 4 VGPR */
typedef __attribute__((ext_vector_type(4))) float f32x4;    /* MFMA C/D */

/* ---- ws layout ----
 * ushort region (from base):
 *   WQB   [256 rows][128 c]            bf16   off 0        (32768)
 *   WKVB  [2 pass][256 rows][128 c]    bf16   off 32768    (65536)
 *   MFOLD [4 b][128 cout][256 hd]      bf16   off 98304    (131072)
 * float region (float offsets):
 *   PART  [512 blk][8 head][1056]      f32    off 114688   (4325376)
 *   PACC  [32 bh][1024]                f32    off 4440064  (32768)
 *   SACC  [32 bh][32]                  f32    off 4472832  (1024)
 * total 4473856 floats = 17.9 MB (round-2 proved >=18.35 MB available)
 */
#define U_WQB    0
#define U_WKVB   32768
#define U_MFOLD  98304
#define F_PART   114688
#define F_PACC   4440064
#define F_SACC   4472832

#define XPITCH 136   /* bf16 elems, x_lds [n][c]: 272B/row = 4 banks offset -> 2-way */
#define KVPITCH 72   /* bf16 elems, kv_lds [row][n]: 144B/row -> 2-way */
#define QPITCH 264   /* bf16 elems, qs_lds [n][hd]: 528B/row -> 2-way */

__device__ __forceinline__ ushort_t f2b(float f) {
    __hip_bfloat16 h = __float2bfloat16(f);
    return *reinterpret_cast<ushort_t*>(&h);
}

__device__ __forceinline__ f32x4 mfma16(bf16x8 a, bf16x8 b, f32x4 c) {
    return __builtin_amdgcn_mfma_f32_16x16x32_bf16(a, b, c, 0, 0, 0);
}

/* ---- prep: cast weights to bf16 in MFMA-A-fragment-friendly row-major layouts ---- */
__global__ void prep_kernel(const float* __restrict__ wqkv, ushort_t* __restrict__ wsb) {
    int idx = blockIdx.x * 256 + threadIdx.x;   /* 384*256 = 98304 */
    if (idx < 32768) {
        /* WQB row rq = h*32+d == wqkv row rq (q block rows 0..255) */
        wsb[U_WQB + idx] = f2b(wqkv[idx]);
    } else {
        int i2 = idx - 32768;
        int p = i2 >> 15, r = (i2 >> 7) & 255, c = i2 & 127;
        int hh = r >> 6, t = (r >> 5) & 1, d = r & 31;
        int src = 256 + t * 256 + (p * 4 + hh) * 32 + d;  /* k rows 256.., v rows 512.. */
        wsb[U_WKVB + i2] = f2b(wqkv[src * 128 + c]);
    }
}

/* ---- Kernel A: k,v logits (MFMA) -> exp -> P=E*V^T and s=E*1 (MFMA) ---- */
__global__ __launch_bounds__(256) void kv_context_kernel(
        const float* __restrict__ x, const ushort_t* __restrict__ wkvb,
        float* __restrict__ part) {
    __shared__ ushort_t x_lds[64 * XPITCH];     /* 17408 B */
    __shared__ ushort_t kv_lds[256 * KVPITCH];  /* 36864 B */
    int blk = blockIdx.x;            /* 512 = b(4) x win(128) */
    int b = blk >> 7, win = blk & 127;
    int tid = threadIdx.x;
    int lane = tid & 63, wv = tid >> 6;
    int l16 = lane & 15, quad = lane >> 4;

    f32x4 accP[2][2][2];   /* [pass][d-tile][e-tile] */
    f32x4 accS[2][2];      /* [pass][d-tile] */
    #pragma unroll
    for (int p = 0; p < 2; ++p)
        #pragma unroll
        for (int i = 0; i < 2; ++i) {
            accS[p][i] = (f32x4){0.f, 0.f, 0.f, 0.f};
            #pragma unroll
            for (int j = 0; j < 2; ++j) accP[p][i][j] = (f32x4){0.f, 0.f, 0.f, 0.f};
        }
    bf16x8 ones;
    #pragma unroll
    for (int j = 0; j < 8; ++j) ones[j] = (short)0x3F80;  /* bf16 1.0 */

    int ct = tid >> 4;             /* staging: c sub-row */
    int n4 = (tid & 15) * 4;       /* staging: 4 consecutive n */

    for (int ch = 0; ch < 4; ++ch) {
        int n0 = win * 256 + ch * 64;
        /* stage x[c][n0..n0+63] -> x_lds[n][c] (bf16, n-major so B-frags are b128) */
        #pragma unroll
        for (int i = 0; i < 8; ++i) {
            int c = i * 16 + ct;
            float4 v = *(const float4*)(x + ((size_t)(b * 128 + c)) * NN + n0 + n4);
            x_lds[(n4 + 0) * XPITCH + c] = f2b(v.x);
            x_lds[(n4 + 1) * XPITCH + c] = f2b(v.y);
            x_lds[(n4 + 2) * XPITCH + c] = f2b(v.z);
            x_lds[(n4 + 3) * XPITCH + c] = f2b(v.w);
        }
        __syncthreads();
        #pragma unroll 1
        for (int p = 0; p < 2; ++p) {
            /* MFMA1: 256 rows (4 heads x {k,v} x 32) x 16 cols (n-tile = wave id) */
            f32x4 acc1[16];
            #pragma unroll
            for (int m = 0; m < 16; ++m) acc1[m] = (f32x4){0.f, 0.f, 0.f, 0.f};
            const ushort_t* wbase = wkvb + (size_t)p * 256 * 128;
            #pragma unroll
            for (int k = 0; k < 4; ++k) {
                bf16x8 bfrag = *(const bf16x8*)&x_lds[(wv * 16 + l16) * XPITCH + k * 32 + quad * 8];
                #pragma unroll
                for (int m = 0; m < 16; ++m) {
                    bf16x8 afrag = *(const bf16x8*)&wbase[(m * 16 + l16) * 128 + k * 32 + quad * 8];
                    acc1[m] = mfma16(afrag, bfrag, acc1[m]);
                }
            }
            /* exp(k-rows) / copy(v-rows) -> kv_lds[row][n] for MFMA2 A/B frags */
            #pragma unroll
            for (int m = 0; m < 16; ++m) {
                int rbase = m * 16 + quad * 4;
                bool isk = ((rbase >> 5) & 1) == 0;   /* row%64 < 32 -> k */
                #pragma unroll
                for (int r = 0; r < 4; ++r) {
                    float v = acc1[m][r];
                    float o = isk ? __expf(v) : v;
                    kv_lds[(rbase + r) * KVPITCH + wv * 16 + l16] = f2b(o);
                }
            }
            __syncthreads();
            /* MFMA2: P[d][e] += E·V^T, s[d] += E·1  (head-in-pass = wave id) */
            {
                const ushort_t* ebase = kv_lds + wv * 64 * KVPITCH;
                const ushort_t* vbase = ebase + 32 * KVPITCH;
                #pragma unroll
                for (int k2 = 0; k2 < 2; ++k2) {
                    int noff = k2 * 32 + quad * 8;
                    bf16x8 ea[2], vb[2];
                    #pragma unroll
                    for (int i = 0; i < 2; ++i) {
                        ea[i] = *(const bf16x8*)&ebase[(i * 16 + l16) * KVPITCH + noff];
                        vb[i] = *(const bf16x8*)&vbase[(i * 16 + l16) * KVPITCH + noff];
                    }
                    #pragma unroll
                    for (int i = 0; i < 2; ++i) {
                        #pragma unroll
                        for (int j = 0; j < 2; ++j)
                            accP[p][i][j] = mfma16(ea[i], vb[j], accP[p][i][j]);
                        accS[p][i] = mfma16(ea[i], ones, accS[p][i]);
                    }
                }
            }
            __syncthreads();
        }
    }
    /* write per-block partials: wave wv owns heads {wv, 4+wv} */
    float* pb = part + (size_t)blk * 8448;
    #pragma unroll
    for (int p = 0; p < 2; ++p) {
        float* ph = pb + (p * 4 + wv) * 1056;
        #pragma unroll
        for (int i = 0; i < 2; ++i)
            #pragma unroll
            for (int j = 0; j < 2; ++j)
                #pragma unroll
                for (int r = 0; r < 4; ++r)
                    ph[(i * 16 + quad * 4 + r) * 32 + j * 16 + l16] = accP[p][i][j][r];
        if (l16 == 0) {
            #pragma unroll
            for (int i = 0; i < 2; ++i)
                #pragma unroll
                for (int r = 0; r < 4; ++r)
                    ph[1024 + i * 16 + quad * 4 + r] = accS[p][i][r];
        }
    }
}

/* ---- B1: reduce per-block partials ---- */
__global__ void reduce_kernel(const float* __restrict__ part,
                              float* __restrict__ Pacc, float* __restrict__ sacc) {
    int bh = blockIdx.x;             /* 32 = b(4) x h(8) */
    int b = bh >> 3, h = bh & 7;
    int tid = threadIdx.x;           /* 256 */
    float a0 = 0.f, a1 = 0.f, a2 = 0.f, a3 = 0.f, s = 0.f;
    const float* pb = part + (size_t)b * 128 * 8448 + h * 1056;
    for (int wnd = 0; wnd < 128; ++wnd) {
        const float* q = pb + (size_t)wnd * 8448;
        a0 += q[tid]; a1 += q[tid + 256]; a2 += q[tid + 512]; a3 += q[tid + 768];
        if (tid < 32) s += q[1024 + tid];
    }
    float* P = Pacc + (size_t)bh * 1024;
    P[tid] = a0; P[tid + 256] = a1; P[tid + 512] = a2; P[tid + 768] = a3;
    if (tid < 32) sacc[bh * 32 + tid] = s;
}

/* ---- B2: Mfold[cout][h*32+d] = sum_e wout[cout][h*32+e] * P[d][e]/s[d], bf16 ---- */
__global__ void context_proj_kernel(const float* __restrict__ wout,
                                    const float* __restrict__ Pacc,
                                    const float* __restrict__ sacc,
                                    ushort_t* __restrict__ mfold) {
    int blk = blockIdx.x;            /* 512 = b(4) x cout(128) */
    int b = blk >> 7, cout = blk & 127;
    int hd = threadIdx.x;            /* 256 */
    int h = hd >> 5, d = hd & 31;
    int bh = b * 8 + h;
    float inv = 1.0f / sacc[bh * 32 + d];
    const float* Pr = Pacc + (size_t)bh * 1024 + d * 32;
    const float* wr = wout + cout * 256 + h * 32;
    float a = 0.f;
    #pragma unroll
    for (int e = 0; e < 32; ++e) a += wr[e] * Pr[e];
    mfold[((size_t)(b * 128 + cout)) * 256 + hd] = f2b(a * inv);
}

/* ---- Kernel C: q logits (MFMA) -> softmax over d -> out = Mfold @ qsm + bias ---- */
__global__ __launch_bounds__(256) void q_out_kernel(
        const float* __restrict__ x, const ushort_t* __restrict__ wqb,
        const ushort_t* __restrict__ mfold, const float* __restrict__ bout,
        float* __restrict__ out) {
    __shared__ ushort_t x_lds[64 * XPITCH];    /* 17408 B */
    __shared__ ushort_t qs_lds[64 * QPITCH];   /* 33792 B */
    int blk = blockIdx.x;            /* 2048 = b(4) x tile(512) */
    int b = blk >> 9, tile = blk & 511;
    int n0 = tile * 64;
    int tid = threadIdx.x;
    int lane = tid & 63, wv = tid >> 6;
    int l16 = lane & 15, quad = lane >> 4;

    /* stage x[c][n0..n0+63] -> x_lds[n][c] bf16 */
    {
        int ct = tid >> 4, n4 = (tid & 15) * 4;
        #pragma unroll
        for (int i = 0; i < 8; ++i) {
            int c = i * 16 + ct;
            float4 v = *(const float4*)(x + ((size_t)(b * 128 + c)) * NN + n0 + n4);
            x_lds[(n4 + 0) * XPITCH + c] = f2b(v.x);
            x_lds[(n4 + 1) * XPITCH + c] = f2b(v.y);
            x_lds[(n4 + 2) * XPITCH + c] = f2b(v.z);
            x_lds[(n4 + 3) * XPITCH + c] = f2b(v.w);
        }
    }
    __syncthreads();
    /* MFMA1: q logits, 16 M-tiles (256 q rows), n-tile = wave id */
    f32x4 acc1[16];
    #pragma unroll
    for (int m = 0; m < 16; ++m) acc1[m] = (f32x4){0.f, 0.f, 0.f, 0.f};
    #pragma unroll
    for (int k = 0; k < 4; ++k) {
        bf16x8 bfrag = *(const bf16x8*)&x_lds[(wv * 16 + l16) * XPITCH + k * 32 + quad * 8];
        #pragma unroll
        for (int m = 0; m < 16; ++m) {
            bf16x8 afrag = *(const bf16x8*)&wqb[(m * 16 + l16) * 128 + k * 32 + quad * 8];
            acc1[m] = mfma16(afrag, bfrag, acc1[m]);
        }
    }
    /* per-head softmax over d (32 rows = tiles 2h,2h+1; cross-quad via shfl) */
    #pragma unroll 1
    for (int h = 0; h < 8; ++h) {
        float mx = -1e30f;
        #pragma unroll
        for (int t = 0; t < 2; ++t)
            #pragma unroll
            for (int r = 0; r < 4; ++r) mx = fmaxf(mx, acc1[2 * h + t][r]);
        mx = fmaxf(mx, __shfl_xor(mx, 16));
        mx = fmaxf(mx, __shfl_xor(mx, 32));
        float e[2][4], sm = 0.f;
        #pragma unroll
        for (int t = 0; t < 2; ++t)
            #pragma unroll
            for (int r = 0; r < 4; ++r) {
                e[t][r] = __expf(acc1[2 * h + t][r] - mx);
                sm += e[t][r];
            }
        sm += __shfl_xor(sm, 16);
        sm += __shfl_xor(sm, 32);
        float sc = QSCALE / sm;
        int n = wv * 16 + l16;
        #pragma unroll
        for (int t = 0; t < 2; ++t)
            #pragma unroll
            for (int r = 0; r < 4; ++r)
                qs_lds[n * QPITCH + h * 32 + t * 16 + quad * 4 + r] = f2b(e[t][r] * sc);
    }
    __syncthreads();
    /* MFMA2: out rows 32*wv..+31 (2 M-tiles) x 4 n-tiles, K=256 (8 steps) */
    f32x4 acc2[2][4];
    #pragma unroll
    for (int mi = 0; mi < 2; ++mi)
        #pragma unroll
        for (int nt = 0; nt < 4; ++nt) acc2[mi][nt] = (f32x4){0.f, 0.f, 0.f, 0.f};
    const ushort_t* mf = mfold + (size_t)b * 128 * 256 + (wv * 32) * 256;
    #pragma unroll
    for (int k = 0; k < 8; ++k) {
        bf16x8 bf[4];
        #pragma unroll
        for (int nt = 0; nt < 4; ++nt)
            bf[nt] = *(const bf16x8*)&qs_lds[(nt * 16 + l16) * QPITCH + k * 32 + quad * 8];
        #pragma unroll
        for (int mi = 0; mi < 2; ++mi) {
            bf16x8 af = *(const bf16x8*)&mf[(mi * 16 + l16) * 256 + k * 32 + quad * 8];
            #pragma unroll
            for (int nt = 0; nt < 4; ++nt)
                acc2[mi][nt] = mfma16(af, bf[nt], acc2[mi][nt]);
        }
    }
    /* bias + store (C-layout: row = quad*4+reg, col = l16 -> coalesced 64B segs) */
    float bias_r[2][4];
    #pragma unroll
    for (int mi = 0; mi < 2; ++mi)
        #pragma unroll
        for (int r = 0; r < 4; ++r)
            bias_r[mi][r] = bout[wv * 32 + mi * 16 + quad * 4 + r];
    #pragma unroll
    for (int mi = 0; mi < 2; ++mi)
        #pragma unroll
        for (int nt = 0; nt < 4; ++nt)
            #pragma unroll
            for (int r = 0; r < 4; ++r) {
                int row = wv * 32 + mi * 16 + quad * 4 + r;
                out[((size_t)(b * 128 + row)) * NN + n0 + nt * 16 + l16] =
                    acc2[mi][nt][r] + bias_r[mi][r];
            }
}

extern "C" void kernel_launch(void* const* d_in, const int* in_sizes, int n_in,
                              void* d_out, int out_size, void* d_ws, size_t ws_size,
                              hipStream_t stream) {
    (void)in_sizes; (void)n_in; (void)out_size; (void)ws_size;
    const float* x    = (const float*)d_in[0];
    const float* wqkv = (const float*)d_in[1];
    const float* wout = (const float*)d_in[2];
    const float* bout = (const float*)d_in[3];
    float* out = (float*)d_out;
    float* ws = (float*)d_ws;
    ushort_t* wsb = (ushort_t*)d_ws;

    prep_kernel<<<384, 256, 0, stream>>>(wqkv, wsb);
    kv_context_kernel<<<512, 256, 0, stream>>>(x, wsb + U_WKVB, ws + F_PART);
    reduce_kernel<<<32, 256, 0, stream>>>(ws + F_PART, ws + F_PACC, ws + F_SACC);
    context_proj_kernel<<<512, 256, 0, stream>>>(wout, ws + F_PACC, ws + F_SACC,
                                                 wsb + U_MFOLD);
    q_out_kernel<<<2048, 256, 0, stream>>>(x, wsb + U_WQB, wsb + U_MFOLD, bout, out);
}

// Round 4
// 379.251 us; speedup vs baseline: 2.3817x; 1.1621x over previous
//
#include <hip/hip_runtime.h>
#include <hip/hip_bf16.h>

#define CC 128
#define NN 32768
#define QSCALE 0.17677669529663687f  /* 1/sqrt(32) */

typedef unsigned short ushort_t;
typedef __attribute__((ext_vector_type(8))) short bf16x8;   /* 8 bf16 = 4 VGPR */
typedef __attribute__((ext_vector_type(4))) short short4v;  /* 4 bf16 = 8 B    */
typedef __attribute__((ext_vector_type(4))) float f32x4;    /* MFMA C/D */

/* ---- ws layout ----
 * ushort region: WQB [256][128] @0 ; WKVB [2][256][128] @32768 ; MFOLD [4][128][256] @98304
 * float  region: PART [512][8][1056] @114688 ; PACC [32][1024] @4440064 ; SACC [32][32] @4472832
 */
#define U_WQB    0
#define U_WKVB   32768
#define U_MFOLD  98304
#define F_PART   114688
#define F_PACC   4440064
#define F_SACC   4472832

#define XPITCH 136   /* bf16: 272 B/row, 16B-aligned, 2-way bank alias (free) */
#define KVPITCH 72   /* bf16: 144 B/row, 16B-aligned, 2-way */
#define QPITCH 264   /* bf16: 528 B/row, 16B-aligned, 2-way */

__device__ __forceinline__ ushort_t f2b(float f) {
    __hip_bfloat16 h = __float2bfloat16(f);
    return *reinterpret_cast<ushort_t*>(&h);
}

__device__ __forceinline__ f32x4 mfma16(bf16x8 a, bf16x8 b, f32x4 c) {
    return __builtin_amdgcn_mfma_f32_16x16x32_bf16(a, b, c, 0, 0, 0);
}

/* ---- prep: cast weights to bf16, MFMA-fragment-friendly row-major ---- */
__global__ void prep_kernel(const float* __restrict__ wqkv, ushort_t* __restrict__ wsb) {
    int idx = blockIdx.x * 256 + threadIdx.x;   /* 384*256 = 98304 */
    if (idx < 32768) {
        wsb[U_WQB + idx] = f2b(wqkv[idx]);      /* q rows 0..255 as-is */
    } else {
        int i2 = idx - 32768;
        int p = i2 >> 15, r = (i2 >> 7) & 255, c = i2 & 127;
        int hh = r >> 6, t = (r >> 5) & 1, d = r & 31;
        int src = 256 + t * 256 + (p * 4 + hh) * 32 + d;  /* k rows 256.., v rows 512.. */
        wsb[U_WKVB + i2] = f2b(wqkv[src * 128 + c]);
    }
}

/* ---- Kernel A: k,v logits (MFMA, swapped operands) -> exp -> P=E*V^T, s=E*1 ---- */
__global__ __launch_bounds__(256, 2) void kv_context_kernel(
        const float* __restrict__ x, const ushort_t* __restrict__ wkvb,
        float* __restrict__ part) {
    __shared__ ushort_t x_lds[64 * XPITCH];     /* 17408 B */
    __shared__ ushort_t kv_lds[256 * KVPITCH];  /* 36864 B */
    int blk = blockIdx.x;            /* 512 = b(4) x win(128) */
    int b = blk >> 7, win = blk & 127;
    int tid = threadIdx.x;
    int lane = tid & 63, wv = tid >> 6;
    int l16 = lane & 15, quad = lane >> 4;

    f32x4 accP[2][2][2];   /* [pass][d-tile][e-tile] */
    f32x4 accS[2][2];      /* [pass][d-tile] */
    #pragma unroll
    for (int p = 0; p < 2; ++p)
        #pragma unroll
        for (int i = 0; i < 2; ++i) {
            accS[p][i] = (f32x4){0.f, 0.f, 0.f, 0.f};
            #pragma unroll
            for (int j = 0; j < 2; ++j) accP[p][i][j] = (f32x4){0.f, 0.f, 0.f, 0.f};
        }
    bf16x8 ones;
    #pragma unroll
    for (int j = 0; j < 8; ++j) ones[j] = (short)0x3F80;  /* bf16 1.0 */

    int ct = tid >> 4, n4 = (tid & 15) * 4;

    for (int ch = 0; ch < 4; ++ch) {
        int n0 = win * 256 + ch * 64;
        /* stage x[c][n0..n0+63] -> x_lds[n][c] bf16 */
        #pragma unroll
        for (int i = 0; i < 8; ++i) {
            int c = i * 16 + ct;
            float4 v = *(const float4*)(x + ((size_t)(b * 128 + c)) * NN + n0 + n4);
            x_lds[(n4 + 0) * XPITCH + c] = f2b(v.x);
            x_lds[(n4 + 1) * XPITCH + c] = f2b(v.y);
            x_lds[(n4 + 2) * XPITCH + c] = f2b(v.z);
            x_lds[(n4 + 3) * XPITCH + c] = f2b(v.w);
        }
        __syncthreads();
        #pragma unroll 1
        for (int p = 0; p < 2; ++p) {
            const ushort_t* wbase = wkvb + (size_t)p * 256 * 128;
            bf16x8 xfrag[4];
            #pragma unroll
            for (int k = 0; k < 4; ++k)
                xfrag[k] = *(const bf16x8*)&x_lds[(wv * 16 + l16) * XPITCH + k * 32 + quad * 8];
            /* MFMA1 tile-at-a-time: D[n][kvrow]; lane: col=kvrow=T*16+l16,
               rows = 4 consecutive n = quad*4+r -> packed b64 LDS write */
            #pragma unroll
            for (int T = 0; T < 16; ++T) {
                f32x4 a = (f32x4){0.f, 0.f, 0.f, 0.f};
                #pragma unroll
                for (int k = 0; k < 4; ++k) {
                    bf16x8 wf = *(const bf16x8*)&wbase[(T * 16 + l16) * 128 + k * 32 + quad * 8];
                    a = mfma16(xfrag[k], wf, a);
                }
                bool isk = (T & 2) == 0;   /* tiles 0,1 of each head-quad = k rows */
                short4v pk;
                #pragma unroll
                for (int r = 0; r < 4; ++r) {
                    float v = a[r];
                    pk[r] = (short)f2b(isk ? __expf(v) : v);
                }
                *(short4v*)&kv_lds[(T * 16 + l16) * KVPITCH + wv * 16 + quad * 4] = pk;
            }
            __syncthreads();
            /* MFMA2: P[d][e] += E·V^T, s[d] += E·1  (head-in-pass = wave id) */
            {
                const ushort_t* ebase = kv_lds + wv * 64 * KVPITCH;
                const ushort_t* vbase = ebase + 32 * KVPITCH;
                #pragma unroll
                for (int k2 = 0; k2 < 2; ++k2) {
                    int noff = k2 * 32 + quad * 8;
                    bf16x8 ea[2], vb[2];
                    #pragma unroll
                    for (int i = 0; i < 2; ++i) {
                        ea[i] = *(const bf16x8*)&ebase[(i * 16 + l16) * KVPITCH + noff];
                        vb[i] = *(const bf16x8*)&vbase[(i * 16 + l16) * KVPITCH + noff];
                    }
                    #pragma unroll
                    for (int i = 0; i < 2; ++i) {
                        #pragma unroll
                        for (int j = 0; j < 2; ++j)
                            accP[p][i][j] = mfma16(ea[i], vb[j], accP[p][i][j]);
                        accS[p][i] = mfma16(ea[i], ones, accS[p][i]);
                    }
                }
            }
            __syncthreads();
        }
    }
    /* per-block partials: wave wv owns head p*4+wv */
    float* pb = part + (size_t)blk * 8448;
    #pragma unroll
    for (int p = 0; p < 2; ++p) {
        float* ph = pb + (p * 4 + wv) * 1056;
        #pragma unroll
        for (int i = 0; i < 2; ++i)
            #pragma unroll
            for (int j = 0; j < 2; ++j)
                #pragma unroll
                for (int r = 0; r < 4; ++r)
                    ph[(i * 16 + quad * 4 + r) * 32 + j * 16 + l16] = accP[p][i][j][r];
        if (l16 == 0) {
            #pragma unroll
            for (int i = 0; i < 2; ++i)
                #pragma unroll
                for (int r = 0; r < 4; ++r)
                    ph[1024 + i * 16 + quad * 4 + r] = accS[p][i][r];
        }
    }
}

/* ---- B1: reduce per-block partials (4x wider than round 3) ---- */
__global__ void reduce_kernel(const float* __restrict__ part,
                              float* __restrict__ Pacc, float* __restrict__ sacc) {
    int blk = blockIdx.x;            /* 128 = bh(32) x chunk(4) */
    int bh = blk >> 2, chunk = blk & 3;
    int b = bh >> 3, h = bh & 7;
    int tid = threadIdx.x;           /* 256 */
    const float* pb = part + (size_t)b * 128 * 8448 + h * 1056;
    float a = 0.f;
    #pragma unroll 4
    for (int wnd = 0; wnd < 128; ++wnd)
        a += pb[(size_t)wnd * 8448 + chunk * 256 + tid];
    Pacc[(size_t)bh * 1024 + chunk * 256 + tid] = a;
    if (chunk == 0 && tid < 32) {
        float s = 0.f;
        #pragma unroll 4
        for (int wnd = 0; wnd < 128; ++wnd)
            s += pb[(size_t)wnd * 8448 + 1024 + tid];
        sacc[bh * 32 + tid] = s;
    }
}

/* ---- B2: Mfold[cout][h*32+d] = sum_e wout[cout][h*32+e] * P[d][e]/s[d] ---- */
__global__ void context_proj_kernel(const float* __restrict__ wout,
                                    const float* __restrict__ Pacc,
                                    const float* __restrict__ sacc,
                                    ushort_t* __restrict__ mfold) {
    int blk = blockIdx.x;            /* 512 = b(4) x cout(128) */
    int b = blk >> 7, cout = blk & 127;
    int hd = threadIdx.x;            /* 256 */
    int h = hd >> 5, d = hd & 31;
    int bh = b * 8 + h;
    float inv = 1.0f / sacc[bh * 32 + d];
    const float* Pr = Pacc + (size_t)bh * 1024 + d * 32;
    const float* wr = wout + cout * 256 + h * 32;
    float a = 0.f;
    #pragma unroll
    for (int e = 0; e < 32; ++e) a += wr[e] * Pr[e];
    mfold[((size_t)(b * 128 + cout)) * 256 + hd] = f2b(a * inv);
}

/* ---- Kernel C: q logits (MFMA, 2 passes) -> softmax over d -> out ---- */
__global__ __launch_bounds__(256, 3) void q_out_kernel(
        const float* __restrict__ x, const ushort_t* __restrict__ wqb,
        const ushort_t* __restrict__ mfold, const float* __restrict__ bout,
        float* __restrict__ out) {
    __shared__ ushort_t x_lds[64 * XPITCH];    /* 17408 B */
    __shared__ ushort_t qs_lds[64 * QPITCH];   /* 33792 B */
    int blk = blockIdx.x;            /* 2048 = b(4) x tile(512) */
    int b = blk >> 9, tile = blk & 511;
    int n0 = tile * 64;
    int tid = threadIdx.x;
    int lane = tid & 63, wv = tid >> 6;
    int l16 = lane & 15, quad = lane >> 4;

    {
        int ct = tid >> 4, n4 = (tid & 15) * 4;
        #pragma unroll
        for (int i = 0; i < 8; ++i) {
            int c = i * 16 + ct;
            float4 v = *(const float4*)(x + ((size_t)(b * 128 + c)) * NN + n0 + n4);
            x_lds[(n4 + 0) * XPITCH + c] = f2b(v.x);
            x_lds[(n4 + 1) * XPITCH + c] = f2b(v.y);
            x_lds[(n4 + 2) * XPITCH + c] = f2b(v.z);
            x_lds[(n4 + 3) * XPITCH + c] = f2b(v.w);
        }
    }
    __syncthreads();
    bf16x8 xfrag[4];
    #pragma unroll
    for (int k = 0; k < 4; ++k)
        xfrag[k] = *(const bf16x8*)&x_lds[(wv * 16 + l16) * XPITCH + k * 32 + quad * 8];
    /* MFMA1 in 2 passes of 8 tiles (4 heads each) to halve live acc regs */
    #pragma unroll 1
    for (int ph = 0; ph < 2; ++ph) {
        f32x4 acc1[8];
        #pragma unroll
        for (int m = 0; m < 8; ++m) acc1[m] = (f32x4){0.f, 0.f, 0.f, 0.f};
        #pragma unroll
        for (int k = 0; k < 4; ++k) {
            #pragma unroll
            for (int m = 0; m < 8; ++m) {
                bf16x8 af = *(const bf16x8*)&wqb[((ph * 8 + m) * 16 + l16) * 128 + k * 32 + quad * 8];
                acc1[m] = mfma16(af, xfrag[k], acc1[m]);
            }
        }
        /* per-head softmax over d; packed b64 qs writes */
        #pragma unroll
        for (int h2 = 0; h2 < 4; ++h2) {
            float mx = -1e30f;
            #pragma unroll
            for (int t = 0; t < 2; ++t)
                #pragma unroll
                for (int r = 0; r < 4; ++r) mx = fmaxf(mx, acc1[2 * h2 + t][r]);
            mx = fmaxf(mx, __shfl_xor(mx, 16));
            mx = fmaxf(mx, __shfl_xor(mx, 32));
            float e[2][4], sm = 0.f;
            #pragma unroll
            for (int t = 0; t < 2; ++t)
                #pragma unroll
                for (int r = 0; r < 4; ++r) {
                    e[t][r] = __expf(acc1[2 * h2 + t][r] - mx);
                    sm += e[t][r];
                }
            sm += __shfl_xor(sm, 16);
            sm += __shfl_xor(sm, 32);
            float sc = QSCALE / sm;
            int n = wv * 16 + l16;
            int hd0 = (ph * 4 + h2) * 32;
            #pragma unroll
            for (int t = 0; t < 2; ++t) {
                short4v pk;
                #pragma unroll
                for (int r = 0; r < 4; ++r) pk[r] = (short)f2b(e[t][r] * sc);
                *(short4v*)&qs_lds[n * QPITCH + hd0 + t * 16 + quad * 4] = pk;
            }
        }
    }
    __syncthreads();
    /* MFMA2: out rows 32*wv..+31 x 4 n-tiles, K=256 */
    f32x4 acc2[2][4];
    #pragma unroll
    for (int mi = 0; mi < 2; ++mi)
        #pragma unroll
        for (int nt = 0; nt < 4; ++nt) acc2[mi][nt] = (f32x4){0.f, 0.f, 0.f, 0.f};
    const ushort_t* mf = mfold + (size_t)b * 128 * 256 + (wv * 32) * 256;
    #pragma unroll
    for (int k = 0; k < 8; ++k) {
        bf16x8 bf[4];
        #pragma unroll
        for (int nt = 0; nt < 4; ++nt)
            bf[nt] = *(const bf16x8*)&qs_lds[(nt * 16 + l16) * QPITCH + k * 32 + quad * 8];
        #pragma unroll
        for (int mi = 0; mi < 2; ++mi) {
            bf16x8 af = *(const bf16x8*)&mf[(mi * 16 + l16) * 256 + k * 32 + quad * 8];
            #pragma unroll
            for (int nt = 0; nt < 4; ++nt)
                acc2[mi][nt] = mfma16(af, bf[nt], acc2[mi][nt]);
        }
    }
    float bias_r[2][4];
    #pragma unroll
    for (int mi = 0; mi < 2; ++mi)
        #pragma unroll
        for (int r = 0; r < 4; ++r)
            bias_r[mi][r] = bout[wv * 32 + mi * 16 + quad * 4 + r];
    #pragma unroll
    for (int mi = 0; mi < 2; ++mi)
        #pragma unroll
        for (int nt = 0; nt < 4; ++nt)
            #pragma unroll
            for (int r = 0; r < 4; ++r) {
                int row = wv * 32 + mi * 16 + quad * 4 + r;
                out[((size_t)(b * 128 + row)) * NN + n0 + nt * 16 + l16] =
                    acc2[mi][nt][r] + bias_r[mi][r];
            }
}

extern "C" void kernel_launch(void* const* d_in, const int* in_sizes, int n_in,
                              void* d_out, int out_size, void* d_ws, size_t ws_size,
                              hipStream_t stream) {
    (void)in_sizes; (void)n_in; (void)out_size; (void)ws_size;
    const float* x    = (const float*)d_in[0];
    const float* wqkv = (const float*)d_in[1];
    const float* wout = (const float*)d_in[2];
    const float* bout = (const float*)d_in[3];
    float* out = (float*)d_out;
    float* ws = (float*)d_ws;
    ushort_t* wsb = (ushort_t*)d_ws;

    prep_kernel<<<384, 256, 0, stream>>>(wqkv, wsb);
    kv_context_kernel<<<512, 256, 0, stream>>>(x, wsb + U_WKVB, ws + F_PART);
    reduce_kernel<<<128, 256, 0, stream>>>(ws + F_PART, ws + F_PACC, ws + F_SACC);
    context_proj_kernel<<<512, 256, 0, stream>>>(wout, ws + F_PACC, ws + F_SACC,
                                                 wsb + U_MFOLD);
    q_out_kernel<<<2048, 256, 0, stream>>>(x, wsb + U_WQB, wsb + U_MFOLD, bout, out);
}

// Round 5
// 258.455 us; speedup vs baseline: 3.4948x; 1.4674x over previous
//
#include <hip/hip_runtime.h>
#include <hip/hip_bf16.h>

#define CC 128
#define NN 32768
#define QSCALE 0.17677669529663687f  /* 1/sqrt(32) */

typedef unsigned short ushort_t;
typedef __attribute__((ext_vector_type(8))) short bf16x8;   /* 8 bf16 = 4 VGPR */
typedef __attribute__((ext_vector_type(4))) short short4v;  /* 4 bf16 = 8 B    */
typedef __attribute__((ext_vector_type(4))) float f32x4;    /* MFMA C/D */

/* ---- ws layout ----
 * ushort region: WQB [256][128] @0 ; WKVB [2][256][128] @32768 ; MFOLD [4][128][256] @98304
 * float  region: PART [512][8][1056] @114688 ; PACC [32][1024] @4440064 ; SACC [32][32] @4472832
 */
#define U_WQB    0
#define U_WKVB   32768
#define U_MFOLD  98304
#define F_PART   114688
#define F_PACC   4440064
#define F_SACC   4472832

#define XPITCH 136   /* bf16: 272 B/row, 16B-aligned, 2-way bank alias (free) */
#define KVP 72       /* bf16: 144 B/row, 16B-aligned */
#define QPITCH 264   /* bf16: 528 B/row, 16B-aligned */

__device__ __forceinline__ ushort_t f2b(float f) {
    __hip_bfloat16 h = __float2bfloat16(f);
    return *reinterpret_cast<ushort_t*>(&h);
}

__device__ __forceinline__ f32x4 mfma16(bf16x8 a, bf16x8 b, f32x4 c) {
    return __builtin_amdgcn_mfma_f32_16x16x32_bf16(a, b, c, 0, 0, 0);
}

/* ---- prep: cast weights to bf16, MFMA-fragment-friendly row-major ---- */
__global__ void prep_kernel(const float* __restrict__ wqkv, ushort_t* __restrict__ wsb) {
    int idx = blockIdx.x * 256 + threadIdx.x;   /* 384*256 = 98304 */
    if (idx < 32768) {
        wsb[U_WQB + idx] = f2b(wqkv[idx]);      /* q rows 0..255 as-is */
    } else {
        int i2 = idx - 32768;
        int p = i2 >> 15, r = (i2 >> 7) & 255, c = i2 & 127;
        int hh = r >> 6, t = (r >> 5) & 1, d = r & 31;
        int src = 256 + t * 256 + (p * 4 + hh) * 32 + d;  /* k rows 256.., v rows 512.. */
        wsb[U_WKVB + i2] = f2b(wqkv[src * 128 + c]);
    }
}

/* ---- Kernel A: head-per-wave. Wave wv computes heads {wv, 4+wv}:
 * MFMA1 D[n][kvrow] over its 64 kv-rows x 64 n, exp, wave-private LDS,
 * MFMA2 P=E*V^T, s=E*1. All register arrays statically indexed. ---- */
__global__ __launch_bounds__(256, 2) void kv_context_kernel(
        const float* __restrict__ x, const ushort_t* __restrict__ wkvb,
        float* __restrict__ part) {
    __shared__ ushort_t x_lds[64 * XPITCH];     /* 17408 B */
    __shared__ ushort_t kv_lds[4 * 64 * KVP];   /* 36864 B, per-wave regions */
    int blk = blockIdx.x;            /* 512 = b(4) x win(128) */
    int b = blk >> 7, win = blk & 127;
    int tid = threadIdx.x;
    int lane = tid & 63, wv = tid >> 6;
    int l16 = lane & 15, quad = lane >> 4;

    f32x4 accP[2][2][2];   /* [pass][d-tile][e-tile] — all indices static */
    f32x4 accS[2][2];
    #pragma unroll
    for (int p = 0; p < 2; ++p)
        #pragma unroll
        for (int i = 0; i < 2; ++i) {
            accS[p][i] = (f32x4){0.f, 0.f, 0.f, 0.f};
            #pragma unroll
            for (int j = 0; j < 2; ++j) accP[p][i][j] = (f32x4){0.f, 0.f, 0.f, 0.f};
        }
    bf16x8 ones;
    #pragma unroll
    for (int j = 0; j < 8; ++j) ones[j] = (short)0x3F80;  /* bf16 1.0 */

    ushort_t* kvw = kv_lds + wv * 64 * KVP;
    int ct = tid >> 4, n4 = (tid & 15) * 4;

    #pragma unroll 1
    for (int ch = 0; ch < 4; ++ch) {
        int n0 = win * 256 + ch * 64;
        /* stage x[c][n0..n0+63] -> x_lds[n][c] bf16 */
        #pragma unroll
        for (int i = 0; i < 8; ++i) {
            int c = i * 16 + ct;
            float4 v = *(const float4*)(x + ((size_t)(b * 128 + c)) * NN + n0 + n4);
            x_lds[(n4 + 0) * XPITCH + c] = f2b(v.x);
            x_lds[(n4 + 1) * XPITCH + c] = f2b(v.y);
            x_lds[(n4 + 2) * XPITCH + c] = f2b(v.z);
            x_lds[(n4 + 3) * XPITCH + c] = f2b(v.w);
        }
        __syncthreads();
        /* all 64 n as A-fragments, reused across both passes */
        bf16x8 xf[4][4];
        #pragma unroll
        for (int s = 0; s < 4; ++s)
            #pragma unroll
            for (int k = 0; k < 4; ++k)
                xf[s][k] = *(const bf16x8*)&x_lds[(s * 16 + l16) * XPITCH + k * 32 + quad * 8];
        #pragma unroll
        for (int p = 0; p < 2; ++p) {
            const ushort_t* wbase = wkvb + (size_t)p * 256 * 128 + (wv * 64) * 128;
            /* MFMA1: 4 row-tiles (2 k-tiles, 2 v-tiles) x 4 n-subtiles */
            #pragma unroll
            for (int T = 0; T < 4; ++T) {
                bf16x8 wf[4];
                #pragma unroll
                for (int k = 0; k < 4; ++k)
                    wf[k] = *(const bf16x8*)&wbase[(T * 16 + l16) * 128 + k * 32 + quad * 8];
                f32x4 a0 = (f32x4){0.f,0.f,0.f,0.f}, a1 = a0, a2 = a0, a3 = a0;
                #pragma unroll
                for (int k = 0; k < 4; ++k) {
                    a0 = mfma16(xf[0][k], wf[k], a0);
                    a1 = mfma16(xf[1][k], wf[k], a1);
                    a2 = mfma16(xf[2][k], wf[k], a2);
                    a3 = mfma16(xf[3][k], wf[k], a3);
                }
                bool isk = T < 2;
                #pragma unroll
                for (int s = 0; s < 4; ++s) {
                    f32x4 a = (s == 0) ? a0 : (s == 1) ? a1 : (s == 2) ? a2 : a3;
                    short4v pk;
                    #pragma unroll
                    for (int r = 0; r < 4; ++r)
                        pk[r] = (short)f2b(isk ? __expf(a[r]) : a[r]);
                    /* row = T*16+l16 (k rows 0..31, v rows 32..63), cols = 4 consecutive n */
                    *(short4v*)&kvw[(T * 16 + l16) * KVP + s * 16 + quad * 4] = pk;
                }
            }
            /* wave-private: only lgkmcnt needed (compiler inserts) */
            #pragma unroll
            for (int k2 = 0; k2 < 2; ++k2) {
                int noff = k2 * 32 + quad * 8;
                bf16x8 ea[2], vb[2];
                #pragma unroll
                for (int i = 0; i < 2; ++i) {
                    ea[i] = *(const bf16x8*)&kvw[(i * 16 + l16) * KVP + noff];
                    vb[i] = *(const bf16x8*)&kvw[(32 + i * 16 + l16) * KVP + noff];
                }
                #pragma unroll
                for (int i = 0; i < 2; ++i) {
                    #pragma unroll
                    for (int j = 0; j < 2; ++j)
                        accP[p][i][j] = mfma16(ea[i], vb[j], accP[p][i][j]);
                    accS[p][i] = mfma16(ea[i], ones, accS[p][i]);
                }
            }
        }
        __syncthreads();   /* x_lds re-staged next chunk */
    }
    /* per-block partials: wave wv owns head p*4+wv */
    float* pb = part + (size_t)blk * 8448;
    #pragma unroll
    for (int p = 0; p < 2; ++p) {
        float* ph = pb + (p * 4 + wv) * 1056;
        #pragma unroll
        for (int i = 0; i < 2; ++i)
            #pragma unroll
            for (int j = 0; j < 2; ++j)
                #pragma unroll
                for (int r = 0; r < 4; ++r)
                    ph[(i * 16 + quad * 4 + r) * 32 + j * 16 + l16] = accP[p][i][j][r];
        if (l16 == 0) {
            #pragma unroll
            for (int i = 0; i < 2; ++i)
                #pragma unroll
                for (int r = 0; r < 4; ++r)
                    ph[1024 + i * 16 + quad * 4 + r] = accS[p][i][r];
        }
    }
}

/* ---- B1: flat reduce — one thread per output element, 128 independent loads ---- */
__global__ void reduce_kernel(const float* __restrict__ part,
                              float* __restrict__ Pacc, float* __restrict__ sacc) {
    int idx = blockIdx.x * 256 + threadIdx.x;   /* 132*256 = 33792 = 32 bh x 1056 */
    if (idx >= 32 * 1056) return;
    int bh = idx / 1056, pos = idx - bh * 1056;
    int b = bh >> 3, h = bh & 7;
    const float* pb = part + (size_t)b * 128 * 8448 + h * 1056 + pos;
    float a = 0.f;
    #pragma unroll 8
    for (int wnd = 0; wnd < 128; ++wnd)
        a += pb[(size_t)wnd * 8448];
    if (pos < 1024) Pacc[(size_t)bh * 1024 + pos] = a;
    else            sacc[bh * 32 + (pos - 1024)] = a;
}

/* ---- B2: Mfold[cout][h*32+d] = sum_e wout[cout][h*32+e] * P[d][e]/s[d] ---- */
__global__ void context_proj_kernel(const float* __restrict__ wout,
                                    const float* __restrict__ Pacc,
                                    const float* __restrict__ sacc,
                                    ushort_t* __restrict__ mfold) {
    int blk = blockIdx.x;            /* 512 = b(4) x cout(128) */
    int b = blk >> 7, cout = blk & 127;
    int hd = threadIdx.x;            /* 256 */
    int h = hd >> 5, d = hd & 31;
    int bh = b * 8 + h;
    float inv = 1.0f / sacc[bh * 32 + d];
    const float* Pr = Pacc + (size_t)bh * 1024 + d * 32;
    const float* wr = wout + cout * 256 + h * 32;
    float a = 0.f;
    #pragma unroll
    for (int e = 0; e < 32; ++e) a += wr[e] * Pr[e];
    mfold[((size_t)(b * 128 + cout)) * 256 + hd] = f2b(a * inv);
}

/* ---- Kernel C: q logits (MFMA, 2 passes) -> softmax over d -> out ---- */
__global__ __launch_bounds__(256, 3) void q_out_kernel(
        const float* __restrict__ x, const ushort_t* __restrict__ wqb,
        const ushort_t* __restrict__ mfold, const float* __restrict__ bout,
        float* __restrict__ out) {
    __shared__ ushort_t x_lds[64 * XPITCH];    /* 17408 B */
    __shared__ ushort_t qs_lds[64 * QPITCH];   /* 33792 B */
    int blk = blockIdx.x;            /* 2048 = b(4) x tile(512) */
    int b = blk >> 9, tile = blk & 511;
    int n0 = tile * 64;
    int tid = threadIdx.x;
    int lane = tid & 63, wv = tid >> 6;
    int l16 = lane & 15, quad = lane >> 4;

    {
        int ct = tid >> 4, n4 = (tid & 15) * 4;
        #pragma unroll
        for (int i = 0; i < 8; ++i) {
            int c = i * 16 + ct;
            float4 v = *(const float4*)(x + ((size_t)(b * 128 + c)) * NN + n0 + n4);
            x_lds[(n4 + 0) * XPITCH + c] = f2b(v.x);
            x_lds[(n4 + 1) * XPITCH + c] = f2b(v.y);
            x_lds[(n4 + 2) * XPITCH + c] = f2b(v.z);
            x_lds[(n4 + 3) * XPITCH + c] = f2b(v.w);
        }
    }
    __syncthreads();
    bf16x8 xfrag[4];
    #pragma unroll
    for (int k = 0; k < 4; ++k)
        xfrag[k] = *(const bf16x8*)&x_lds[(wv * 16 + l16) * XPITCH + k * 32 + quad * 8];
    #pragma unroll 1
    for (int ph = 0; ph < 2; ++ph) {
        f32x4 acc1[8];
        #pragma unroll
        for (int m = 0; m < 8; ++m) acc1[m] = (f32x4){0.f, 0.f, 0.f, 0.f};
        #pragma unroll
        for (int k = 0; k < 4; ++k) {
            #pragma unroll
            for (int m = 0; m < 8; ++m) {
                bf16x8 af = *(const bf16x8*)&wqb[((ph * 8 + m) * 16 + l16) * 128 + k * 32 + quad * 8];
                acc1[m] = mfma16(af, xfrag[k], acc1[m]);
            }
        }
        #pragma unroll
        for (int h2 = 0; h2 < 4; ++h2) {
            float mx = -1e30f;
            #pragma unroll
            for (int t = 0; t < 2; ++t)
                #pragma unroll
                for (int r = 0; r < 4; ++r) mx = fmaxf(mx, acc1[2 * h2 + t][r]);
            mx = fmaxf(mx, __shfl_xor(mx, 16));
            mx = fmaxf(mx, __shfl_xor(mx, 32));
            float e[2][4], sm = 0.f;
            #pragma unroll
            for (int t = 0; t < 2; ++t)
                #pragma unroll
                for (int r = 0; r < 4; ++r) {
                    e[t][r] = __expf(acc1[2 * h2 + t][r] - mx);
                    sm += e[t][r];
                }
            sm += __shfl_xor(sm, 16);
            sm += __shfl_xor(sm, 32);
            float sc = QSCALE / sm;
            int n = wv * 16 + l16;
            int hd0 = (ph * 4 + h2) * 32;
            #pragma unroll
            for (int t = 0; t < 2; ++t) {
                short4v pk;
                #pragma unroll
                for (int r = 0; r < 4; ++r) pk[r] = (short)f2b(e[t][r] * sc);
                *(short4v*)&qs_lds[n * QPITCH + hd0 + t * 16 + quad * 4] = pk;
            }
        }
    }
    __syncthreads();
    f32x4 acc2[2][4];
    #pragma unroll
    for (int mi = 0; mi < 2; ++mi)
        #pragma unroll
        for (int nt = 0; nt < 4; ++nt) acc2[mi][nt] = (f32x4){0.f, 0.f, 0.f, 0.f};
    const ushort_t* mf = mfold + (size_t)b * 128 * 256 + (wv * 32) * 256;
    #pragma unroll
    for (int k = 0; k < 8; ++k) {
        bf16x8 bf[4];
        #pragma unroll
        for (int nt = 0; nt < 4; ++nt)
            bf[nt] = *(const bf16x8*)&qs_lds[(nt * 16 + l16) * QPITCH + k * 32 + quad * 8];
        #pragma unroll
        for (int mi = 0; mi < 2; ++mi) {
            bf16x8 af = *(const bf16x8*)&mf[(mi * 16 + l16) * 256 + k * 32 + quad * 8];
            #pragma unroll
            for (int nt = 0; nt < 4; ++nt)
                acc2[mi][nt] = mfma16(af, bf[nt], acc2[mi][nt]);
        }
    }
    float bias_r[2][4];
    #pragma unroll
    for (int mi = 0; mi < 2; ++mi)
        #pragma unroll
        for (int r = 0; r < 4; ++r)
            bias_r[mi][r] = bout[wv * 32 + mi * 16 + quad * 4 + r];
    #pragma unroll
    for (int mi = 0; mi < 2; ++mi)
        #pragma unroll
        for (int nt = 0; nt < 4; ++nt)
            #pragma unroll
            for (int r = 0; r < 4; ++r) {
                int row = wv * 32 + mi * 16 + quad * 4 + r;
                out[((size_t)(b * 128 + row)) * NN + n0 + nt * 16 + l16] =
                    acc2[mi][nt][r] + bias_r[mi][r];
            }
}

extern "C" void kernel_launch(void* const* d_in, const int* in_sizes, int n_in,
                              void* d_out, int out_size, void* d_ws, size_t ws_size,
                              hipStream_t stream) {
    (void)in_sizes; (void)n_in; (void)out_size; (void)ws_size;
    const float* x    = (const float*)d_in[0];
    const float* wqkv = (const float*)d_in[1];
    const float* wout = (const float*)d_in[2];
    const float* bout = (const float*)d_in[3];
    float* out = (float*)d_out;
    float* ws = (float*)d_ws;
    ushort_t* wsb = (ushort_t*)d_ws;

    prep_kernel<<<384, 256, 0, stream>>>(wqkv, wsb);
    kv_context_kernel<<<512, 256, 0, stream>>>(x, wsb + U_WKVB, ws + F_PART);
    reduce_kernel<<<132, 256, 0, stream>>>(ws + F_PART, ws + F_PACC, ws + F_SACC);
    context_proj_kernel<<<512, 256, 0, stream>>>(wout, ws + F_PACC, ws + F_SACC,
                                                 wsb + U_MFOLD);
    q_out_kernel<<<2048, 256, 0, stream>>>(x, wsb + U_WQB, wsb + U_MFOLD, bout, out);
}